// Round 10
// baseline (3240.961 us; speedup 1.0000x reference)
//
#include <hip/hip_runtime.h>
#include <hip/hip_bf16.h>

// Problem constants
#define B_   64
#define T_   512
#define I_   512
#define H_   512
#define G_   5
#define NROW 2560   // G*H gate rows per direction
#define KD   512    // K depth
#define NBLK_REC 128

typedef __attribute__((ext_vector_type(8))) __bf16 bf16x8;
typedef __attribute__((ext_vector_type(4))) float  f32x4;
typedef __attribute__((ext_vector_type(2))) unsigned long long u64x2;
typedef unsigned long long u64;

#define MFMA16(A, Bf, C) __builtin_amdgcn_mfma_f32_16x16x32_bf16(A, Bf, C, 0, 0, 0)

__device__ __forceinline__ unsigned short f2bf(float f) {
  unsigned u = __builtin_bit_cast(unsigned, f);
  u = (u + 0x7fffu + ((u >> 16) & 1u)) >> 16;   // RNE
  return (unsigned short)u;
}
__device__ __forceinline__ float bf2f(unsigned short s) {
  unsigned u = ((unsigned)s) << 16;
  return __builtin_bit_cast(float, u);
}
__device__ __forceinline__ float sigm(float x) { return 1.f / (1.f + __expf(-x)); }
__device__ __forceinline__ float tanh_fast(float x) {
  return 1.f - 2.f / (__expf(2.f * x) + 1.f);
}
__device__ __forceinline__ u64 al64(const u64* p) {
  return __hip_atomic_load(p, __ATOMIC_RELAXED, __HIP_MEMORY_SCOPE_AGENT);
}
__device__ __forceinline__ unsigned al32(const unsigned* p) {
  return __hip_atomic_load(p, __ATOMIC_RELAXED, __HIP_MEMORY_SCOPE_AGENT);
}
__device__ __forceinline__ void st32(unsigned* p, unsigned v) {
  __hip_atomic_store(p, v, __ATOMIC_RELAXED, __HIP_MEMORY_SCOPE_AGENT);
}
// asm-opaque pin: value must stay live in the register file
__device__ __forceinline__ void pin_v(bf16x8& v) { asm volatile("" : "+v"(v)); }

// ---------------- ws layout (bytes) ----------------
#define OFF_XP   ((size_t)0)
#define OFF_XB   ((size_t)335544320)
#define OFF_W2X  ((size_t)369098752)
#define OFF_W2H  ((size_t)374341632)
#define OFF_BIAS ((size_t)379584512)
#define OFF_HB   ((size_t)379604992)
#define OFF_BAR  ((size_t)379867136)
#define WS_NEED  ((size_t)379871232)

// ---------------- sentinel (ws too small) ----------------
__global__ void k_sentinel(float* out, int n) {
  int i = blockIdx.x * 256 + threadIdx.x;
  if (i < n) out[i] = 10000.0f;
}

// ---------------- converts ----------------
__global__ void k_cvt_weights(const float* __restrict__ Wx_f, const float* __restrict__ Wh_f,
                              const float* __restrict__ Wx_b, const float* __restrict__ Wh_b,
                              const float* __restrict__ bx_f, const float* __restrict__ bh_f,
                              const float* __restrict__ bx_b, const float* __restrict__ bh_b,
                              unsigned short* __restrict__ W2x, unsigned short* __restrict__ W2h,
                              float* __restrict__ bias2) {
  int idx = blockIdx.x * 256 + threadIdx.x;       // exactly 2*NROW*KD threads
  int dir = idx / (NROW * KD);
  int r   = idx % (NROW * KD);
  W2x[idx] = f2bf(dir ? Wx_b[r] : Wx_f[r]);
  W2h[idx] = f2bf(dir ? Wh_b[r] : Wh_f[r]);
  if (idx < 2 * NROW) {
    int d2 = idx / NROW, n = idx % NROW;
    bias2[idx] = d2 ? (bx_b[n] + bh_b[n]) : (bx_f[n] + bh_f[n]);
  }
}

__global__ void k_cvt_x(const float* __restrict__ x, unsigned short* __restrict__ xb) {
  int idx = blockIdx.x * 256 + threadIdx.x;       // exactly B*T*I threads
  xb[idx] = f2bf(x[idx]);
}

__global__ void k_zero_h(unsigned short* __restrict__ hb, unsigned* __restrict__ bar) {
  int idx = blockIdx.x * 256 + threadIdx.x;       // exactly 2*2*B*H threads
  hb[idx] = 0;
  if (idx < 1024) bar[idx] = 0;
}

// ---------------- phase 1: xp = Wx · x^T (+bias), both dirs ----------------
__global__ __launch_bounds__(256) void k_gemm_xp(
    const unsigned short* __restrict__ W2x,   // [2][NROW][KD]
    const unsigned short* __restrict__ xb,    // [B][T][I]
    const float* __restrict__ bias2,          // [2][NROW]
    unsigned short* __restrict__ xp)          // [2][T][NROW][B]
{
  const int tid = threadIdx.x;
  const int lane = tid & 63, wv = tid >> 6;
  int bz = blockIdx.x;
  const int dir = bz / (20 * 256); bz %= (20 * 256);
  const int nblk = bz / 256, mblk = bz % 256;
  const int n0 = nblk * 128, m0 = mblk * 128;
  const int l15 = lane & 15, l4 = lane >> 4;
  const int nh = wv >> 1, mh = wv & 1;

  __shared__ unsigned short Al[128 * 72];
  __shared__ unsigned short Bl[128 * 72];

  const unsigned short* Wd = W2x + (size_t)dir * NROW * KD;

  f32x4 acc[4][4];
  f32x4 zz = {0.f, 0.f, 0.f, 0.f};
#pragma unroll
  for (int i = 0; i < 4; ++i)
#pragma unroll
    for (int j = 0; j < 4; ++j) acc[i][j] = zz;

  for (int k0 = 0; k0 < KD; k0 += 64) {
#pragma unroll
    for (int j = 0; j < 4; ++j) {
      int sg = j * 256 + tid;
      int row = sg >> 3, ko = (sg & 7) * 8;
      bf16x8 va = *(const bf16x8*)(Wd + (size_t)(n0 + row) * KD + k0 + ko);
      *(bf16x8*)(Al + row * 72 + ko) = va;
      int m = m0 + row;
      int ss = m >> 6, b = m & 63;
      int trow = dir ? (T_ - 1 - ss) : ss;
      bf16x8 vb = *(const bf16x8*)(xb + ((size_t)b * T_ + trow) * I_ + k0 + ko);
      *(bf16x8*)(Bl + row * 72 + ko) = vb;
    }
    __syncthreads();
#pragma unroll
    for (int kk = 0; kk < 2; ++kk) {
      bf16x8 af[4], bfr[4];
#pragma unroll
      for (int f = 0; f < 4; ++f) {
        af[f]  = *(const bf16x8*)(Al + (nh * 64 + f * 16 + l15) * 72 + kk * 32 + l4 * 8);
        bfr[f] = *(const bf16x8*)(Bl + (mh * 64 + f * 16 + l15) * 72 + kk * 32 + l4 * 8);
      }
#pragma unroll
      for (int fi = 0; fi < 4; ++fi)
#pragma unroll
        for (int fj = 0; fj < 4; ++fj)
          acc[fi][fj] = MFMA16(af[fi], bfr[fj], acc[fi][fj]);
    }
    __syncthreads();
  }

#pragma unroll
  for (int fi = 0; fi < 4; ++fi) {
#pragma unroll
    for (int fj = 0; fj < 4; ++fj) {
#pragma unroll
      for (int r = 0; r < 4; ++r) {
        int n = n0 + nh * 64 + fi * 16 + l4 * 4 + r;
        int m = m0 + mh * 64 + fj * 16 + l15;
        int ss = m >> 6, b = m & 63;
        float v = acc[fi][fj][r] + bias2[dir * NROW + n];
        xp[(((size_t)dir * T_ + ss) * NROW + n) * 64 + b] = f2bf(v);
      }
    }
  }
}

// ---------------- phase 2: wave-specialized persistent kernel ----------------
// 128 blocks x 4 waves. Waves 0-1 -> dir f, waves 2-3 -> dir b (concurrent).
// Block bid owns units bid*4..bid*4+3 of each dir; wave handles 32 batches.
// Per wave per step: 64 u64 h loads (L3, agent atomics) -> 64 MFMA (weights
// asm-pinned in registers) -> private LDS gate strip (wave-internal lgkmcnt,
// NO s_barrier) -> cell update -> coalesced h store -> vmcnt(0) -> own flag.
// 256 wave-flags per dir; poll = 4 coalesced line loads + __any.
__global__ __launch_bounds__(256, 1) void k_recurrent(
    const unsigned short* __restrict__ W2h,  // [2][NROW][KD]
    const unsigned short* __restrict__ xp,   // [2][T][NROW][B]
    unsigned short* __restrict__ hbuf,       // [buf][dir][128 c][64 b][4 u]
    float* __restrict__ out,                 // [B][T][2H]
    unsigned* __restrict__ bar)              // [2][256] wave-flags
{
  const int tid = threadIdx.x;
  const int lane = tid & 63, wv = tid >> 6;
  const int bid = blockIdx.x;
  const int dirw = wv >> 1;                  // 0 = f, 1 = b
  const int mh   = wv & 1;                   // batch half (0: b0-31, 1: b32-63)
  const int l15 = lane & 15, l4 = lane >> 4;

  __shared__ float g_sh[4][32 * 21];         // per-wave private gate strips
  float* gl = g_sh[wv];

  // ---- load + pin 32 weight fragments (2 N-tiles x 16 ks), once ----
  bf16x8 wf0[16], wf1[16];
  {
    const unsigned short* w0 =
        W2h + ((size_t)dirw * NROW + (l15 >> 2) * H_ + bid * 4 + (l15 & 3)) * KD;
    int r1 = 16 + l15; if (r1 >= 20) r1 = 0;   // pad rows -> row 0 (unused cols)
    const unsigned short* w1 =
        W2h + ((size_t)dirw * NROW + (r1 >> 2) * H_ + bid * 4 + (r1 & 3)) * KD;
#pragma unroll
    for (int ks = 0; ks < 16; ++ks) {
      wf0[ks] = *(const bf16x8*)(w0 + ks * 32 + l4 * 8);
      wf1[ks] = *(const bf16x8*)(w1 + ks * 32 + l4 * 8);
      pin_v(wf0[ks]); pin_v(wf1[ks]);
    }
  }

  const unsigned short* xpd = xp + (size_t)dirw * T_ * NROW * 64;
  const unsigned short* hc = hbuf + (size_t)dirw * B_ * H_;        // buf 0
  unsigned short*       hn = hbuf + (size_t)(2 + dirw) * B_ * H_;  // buf 1
  unsigned* fl = bar + dirw * 256;
  const int myflag = bid * 2 + mh;

  // cell mapping: lane -> batch bl = lane>>1 (local 0..31), unit pair up2
  const int bl  = lane >> 1;
  const int bg  = mh * 32 + bl;              // global batch
  const int up2 = (lane & 1) * 2;            // local unit pair base (0 or 2)
  float kst0 = 0.f, kp0 = 0.f, kst1 = 0.f, kp1 = 0.f;

  // xp prefetch for s = 0 (10 scalar bf16 loads)
  unsigned short xr0[5], xr1[5];
#pragma unroll
  for (int g = 0; g < 5; ++g) {
    xr0[g] = xpd[((size_t)g * H_ + bid * 4 + up2) * 64 + bg];
    xr1[g] = xpd[((size_t)g * H_ + bid * 4 + up2 + 1) * 64 + bg];
  }

  for (int s = 0; s < T_; ++s) {
    if (s) {
      __builtin_amdgcn_sched_barrier(0);
      unsigned tgt = (unsigned)s;
      for (;;) {
        unsigned a = al32(fl + lane);
        unsigned b = al32(fl + 64 + lane);
        unsigned c = al32(fl + 128 + lane);
        unsigned d = al32(fl + 192 + lane);
        unsigned m0 = a < b ? a : b, m1 = c < d ? c : d;
        unsigned v = m0 < m1 ? m0 : m1;
        if (!__any(v < tgt)) break;
        __builtin_amdgcn_s_sleep(1);
      }
      __builtin_amdgcn_sched_barrier(0);
    }

    const u64* hq = (const u64*)hc;
    f32x4 zz4 = {0.f, 0.f, 0.f, 0.f};
    f32x4 acc00 = zz4, acc01 = zz4, acc10 = zz4, acc11 = zz4;
    // M-tile 0 (batches mh*32 .. +15)
    {
      int batch = mh * 32 + l15;
      u64 lo[16], hi[16];
#pragma unroll
      for (int ks = 0; ks < 16; ++ks) {
        int c = ks * 8 + l4 * 2;
        lo[ks] = al64(hq + c * 64 + batch);
        hi[ks] = al64(hq + (c + 1) * 64 + batch);
      }
#pragma unroll
      for (int ks = 0; ks < 16; ++ks) {
        u64x2 t2 = {lo[ks], hi[ks]};
        bf16x8 a = __builtin_bit_cast(bf16x8, t2);
        acc00 = MFMA16(a, wf0[ks], acc00);
        acc01 = MFMA16(a, wf1[ks], acc01);
      }
    }
    // M-tile 1 (batches mh*32+16 .. +31)
    {
      int batch = mh * 32 + 16 + l15;
      u64 lo[16], hi[16];
#pragma unroll
      for (int ks = 0; ks < 16; ++ks) {
        int c = ks * 8 + l4 * 2;
        lo[ks] = al64(hq + c * 64 + batch);
        hi[ks] = al64(hq + (c + 1) * 64 + batch);
      }
#pragma unroll
      for (int ks = 0; ks < 16; ++ks) {
        u64x2 t2 = {lo[ks], hi[ks]};
        bf16x8 a = __builtin_bit_cast(bf16x8, t2);
        acc10 = MFMA16(a, wf0[ks], acc10);
        acc11 = MFMA16(a, wf1[ks], acc11);
      }
    }

    // dump D to this wave's private strip: row=batch (l4*4+rr), col=gate row
#pragma unroll
    for (int rr = 0; rr < 4; ++rr) {
      int b0 = l4 * 4 + rr;
      gl[b0 * 21 + l15] = acc00[rr];
      if (l15 < 4) gl[b0 * 21 + 16 + l15] = acc01[rr];
      int b1 = 16 + l4 * 4 + rr;
      gl[b1 * 21 + l15] = acc10[rr];
      if (l15 < 4) gl[b1 * 21 + 16 + l15] = acc11[rr];
    }
    asm volatile("s_waitcnt lgkmcnt(0)" ::: "memory");  // wave-internal only
    __builtin_amdgcn_sched_barrier(0);

    // cell update: 2 cells (bg, bid*4+up2) and (bg, bid*4+up2+1)
    float p[5], q[5];
#pragma unroll
    for (int g = 0; g < 5; ++g) {
      p[g] = gl[bl * 21 + g * 4 + up2]     + bf2f(xr0[g]);
      q[g] = gl[bl * 21 + g * 4 + up2 + 1] + bf2f(xr1[g]);
    }
    float f0 = sigm(p[0]), i0 = sigm(p[1]), o0 = sigm(p[2]), u0 = sigm(p[3]), t0 = tanh_fast(p[4]);
    kp0  = u0 * t0 + (1.f - u0) * kp0;
    kst0 = f0 * kst0 + i0 * kp0;
    float hv0 = o0 * tanh_fast(kst0);
    float f1 = sigm(q[0]), i1 = sigm(q[1]), o1 = sigm(q[2]), u1 = sigm(q[3]), t1 = tanh_fast(q[4]);
    kp1  = u1 * t1 + (1.f - u1) * kp1;
    kst1 = f1 * kst1 + i1 * kp1;
    float hv1 = o1 * tanh_fast(kst1);

    // publish h: u32 (2 units), 64 lanes -> 256B contiguous per wave
    unsigned hw = (unsigned)f2bf(hv0) | ((unsigned)f2bf(hv1) << 16);
    st32((unsigned*)hn + bid * 128 + bg * 2 + (lane & 1), hw);

    int tout = dirw ? (T_ - 1 - s) : s;
    float2 ov = {hv0, hv1};
    if (s + 1 < T_) {
      asm volatile("s_waitcnt vmcnt(0)" ::: "memory");   // h store acked
      st32(&fl[myflag], (unsigned)(s + 1));              // own wave-flag
      // off-critical-path: out store + xp prefetch overlap the next poll
      *(float2*)&out[((size_t)bg * T_ + tout) * (2 * H_) + dirw * H_ + bid * 4 + up2] = ov;
      const unsigned short* nx = xpd + (size_t)(s + 1) * NROW * 64;
#pragma unroll
      for (int g = 0; g < 5; ++g) {
        xr0[g] = nx[((size_t)g * H_ + bid * 4 + up2) * 64 + bg];
        xr1[g] = nx[((size_t)g * H_ + bid * 4 + up2 + 1) * 64 + bg];
      }
    } else {
      *(float2*)&out[((size_t)bg * T_ + tout) * (2 * H_) + dirw * H_ + bid * 4 + up2] = ov;
    }

    const unsigned short* tp = hc; hc = hn; hn = (unsigned short*)tp;
  }
}

// ---------------- launch ----------------
extern "C" void kernel_launch(void* const* d_in, const int* in_sizes, int n_in,
                              void* d_out, int out_size, void* d_ws, size_t ws_size,
                              hipStream_t stream) {
  const float* x    = (const float*)d_in[0];
  const float* Wx_f = (const float*)d_in[1];
  const float* bx_f = (const float*)d_in[2];
  const float* Wh_f = (const float*)d_in[3];
  const float* bh_f = (const float*)d_in[4];
  const float* Wx_b = (const float*)d_in[5];
  const float* bx_b = (const float*)d_in[6];
  const float* Wh_b = (const float*)d_in[7];
  const float* bh_b = (const float*)d_in[8];
  float* out = (float*)d_out;

  if (ws_size < WS_NEED) {
    k_sentinel<<<(out_size + 255) / 256, 256, 0, stream>>>(out, out_size);
    return;
  }

  char* ws = (char*)d_ws;
  unsigned short* xp    = (unsigned short*)(ws + OFF_XP);
  unsigned short* xb    = (unsigned short*)(ws + OFF_XB);
  unsigned short* W2x   = (unsigned short*)(ws + OFF_W2X);
  unsigned short* W2h   = (unsigned short*)(ws + OFF_W2H);
  float*          bias2 = (float*)(ws + OFF_BIAS);
  unsigned short* hbuf  = (unsigned short*)(ws + OFF_HB);
  unsigned*       bar   = (unsigned*)(ws + OFF_BAR);

  k_cvt_weights<<<(2 * NROW * KD) / 256, 256, 0, stream>>>(
      Wx_f, Wh_f, Wx_b, Wh_b, bx_f, bh_f, bx_b, bh_b, W2x, W2h, bias2);
  k_cvt_x<<<(B_ * T_ * I_) / 256, 256, 0, stream>>>(x, xb);
  k_zero_h<<<(2 * 2 * B_ * H_) / 256, 256, 0, stream>>>(hbuf, bar);
  k_gemm_xp<<<2 * 20 * 256, 256, 0, stream>>>(W2x, xb, bias2, xp);
  k_recurrent<<<NBLK_REC, 256, 0, stream>>>(W2h, xp, hbuf, out, bar);
}